// Round 14
// baseline (460.505 us; speedup 1.0000x reference)
//
#include <hip/hip_runtime.h>
#include <hip/hip_bf16.h>

#define TEMP_INV 14.285714285714286f  // 1/0.07
#define FSCALE 16.0f                  // fp8 pre-scale per operand
#define T1S (TEMP_INV / 256.0f)       // acc = 256*sim -> (sim-1)/T = acc*T1S - TEMP_INV

typedef __attribute__((ext_vector_type(4))) float f32x4;
typedef __attribute__((ext_vector_type(4))) int i32x4;
typedef __attribute__((ext_vector_type(8))) int i32x8;

#define ASYNC_COPY16(gp, lp)                                                  \
  __builtin_amdgcn_global_load_lds(                                          \
      (__attribute__((address_space(1))) const void*)(gp),                    \
      (__attribute__((address_space(3))) void*)(lp), 16, 0, 0)

// ---- row L2-normalize -> fp8 e4m3 (x16) in QUAD-MAJOR layout ----
__global__ __launch_bounds__(256) void norm_k(const float* __restrict__ feat,
                                              uchar* __restrict__ fq,
                                              const int* __restrict__ labels,
                                              const int* __restrict__ kptr,
                                              int* __restrict__ glab,
                                              float* __restrict__ gacc,
                                              int* __restrict__ dcnt,
                                              int N, int D) {
  const int row = (blockIdx.x * 256 + threadIdx.x) >> 6;
  const int lane = threadIdx.x & 63;
  if (row < N) {
    const float4* fr = (const float4*)(feat + (size_t)row * D);
    float4 v0 = fr[lane * 2];
    float4 v1 = fr[lane * 2 + 1];
    float ss = v0.x * v0.x + v0.y * v0.y + v0.z * v0.z + v0.w * v0.w +
               v1.x * v1.x + v1.y * v1.y + v1.z * v1.z + v1.w * v1.w;
    #pragma unroll
    for (int off = 32; off; off >>= 1) ss += __shfl_xor(ss, off, 64);
    const float inv = FSCALE / fmaxf(sqrtf(ss), 1e-12f);
    int w0 = 0, w1 = 0;
    w0 = __builtin_amdgcn_cvt_pk_fp8_f32(v0.x * inv, v0.y * inv, w0, false);
    w0 = __builtin_amdgcn_cvt_pk_fp8_f32(v0.z * inv, v0.w * inv, w0, true);
    w1 = __builtin_amdgcn_cvt_pk_fp8_f32(v1.x * inv, v1.y * inv, w1, false);
    w1 = __builtin_amdgcn_cvt_pk_fp8_f32(v1.z * inv, v1.w * inv, w1, true);
    uint2 o; o.x = (uint)w0; o.y = (uint)w1;
    const int pofs = (lane >> 4) * 128 + (lane & 3) * 32 + ((lane >> 2) & 3) * 8;
    *(uint2*)(fq + (size_t)row * D + pofs) = o;
    if (lane == 0) {
      const int k = *kptr;
      glab[row] = labels[(size_t)(row / k) * k];
    }
  }
  if (blockIdx.x == 0 && threadIdx.x < 3) {
    if (threadIdx.x < 2) gacc[threadIdx.x] = 0.f;
    else *dcnt = 0;
  }
}

// ---- fused MX-fp8 GEMM + masked-softmax-stats, PERSISTENT TILE PAIRS ----
// Each block handles 2 consecutive upper-triangle tiles. After tile 1's last
// k-iter (post-barrier, LDS free), tile 2's iter-0 DMAs are issued and their
// drain latency is covered by tile 1's epilogue VALU (stats live in a
// separate 4 KB LDS array, not As/Bs). Hides 1 of 4 drains per tile.
__global__ __launch_bounds__(256, 4) void gemm_k(const uchar* __restrict__ fq,
                                                 const int* __restrict__ glab,
                                                 float* __restrict__ part,
                                                 int N, int D) {
  __shared__ uchar As[128 * 128];
  __shared__ uchar Bs[128 * 128];
  __shared__ float sf[1024];
  const int t = threadIdx.x;
  const int lane = t & 63;
  const int wid = t >> 6;
  const int wrow = wid >> 1, wcol = wid & 1;
  const int quad = lane >> 4, l15 = lane & 15;

  const int nb = N / 128;
  const int total = nb * (nb + 1) / 2;
  // XCD-band remap of tile PAIRS: contiguous pair-band per XCD
  int gidx;
  if ((total & 15) == 0) {
    const int perx = total >> 4;  // pairs per XCD
    gidx = ((blockIdx.x & 7) * perx + (blockIdx.x >> 3)) * 2;
  } else {
    gidx = blockIdx.x * 2;
  }
  int idx = gidx, bi = 0;
  while (idx >= nb - bi) { idx -= nb - bi; bi++; }
  int bj = bi + idx;
  int i0 = bi * 128, j0 = bj * 128;

  const int lrow = lane >> 3;  // 0..7: row within one 8-row DMA group
  const int lch = lane & 7;    // 16B LDS chunk written by this lane
  uchar* sb = (wid < 2) ? As : Bs;
  const int rbase = (wid & 1) * 64;

  #define ISSUE_DMA(ri0, rj0, kb)                                             \
    {                                                                         \
      const int rowstart = ((wid < 2) ? (ri0) : (rj0)) + rbase;               \
      _Pragma("unroll")                                                       \
      for (int i8 = 0; i8 < 8; i8++) {                                        \
        const int rl = 8 * i8 + lrow;                                         \
        const int cg = lch ^ (rl & 7);                                        \
        ASYNC_COPY16(fq + (size_t)(rowstart + rl) * D + (kb) + cg * 16,       \
                     sb + (rbase + 8 * i8) * 128);                            \
      }                                                                       \
    }

  // prologue: stage tile-1 iter0 and drain
  ISSUE_DMA(i0, j0, 0)
  __syncthreads();

  for (int tt = 0; tt < 2; tt++) {
    const bool diagblk = (bi == bj);
    const bool valid = (gidx < total);

    f32x4 acc[4][4];
    #pragma unroll
    for (int mi = 0; mi < 4; mi++)
      #pragma unroll
      for (int ni = 0; ni < 4; ni++) {
        f32x4 z = {0.f, 0.f, 0.f, 0.f};
        acc[mi][ni] = z;
      }

    // K-loop: iter-`it` data is staged+drained on entry
    for (int it = 0; it < 4; it++) {
      i32x8 av[4];
      #pragma unroll
      for (int mi = 0; mi < 4; mi++) {
        const int r = wrow * 64 + mi * 16 + l15;
        i32x4 lo = *(const i32x4*)&As[r * 128 + (((2 * quad) ^ (r & 7)) << 4)];
        i32x4 hi = *(const i32x4*)&As[r * 128 + (((2 * quad + 1) ^ (r & 7)) << 4)];
        av[mi] = (i32x8){lo.x, lo.y, lo.z, lo.w, hi.x, hi.y, hi.z, hi.w};
      }
      #pragma unroll
      for (int ni = 0; ni < 4; ni++) {
        const int r = wcol * 64 + ni * 16 + l15;
        i32x4 lo = *(const i32x4*)&Bs[r * 128 + (((2 * quad) ^ (r & 7)) << 4)];
        i32x4 hi = *(const i32x4*)&Bs[r * 128 + (((2 * quad + 1) ^ (r & 7)) << 4)];
        i32x8 bv = (i32x8){lo.x, lo.y, lo.z, lo.w, hi.x, hi.y, hi.z, hi.w};
        #pragma unroll
        for (int mi = 0; mi < 4; mi++)
          acc[mi][ni] = __builtin_amdgcn_mfma_scale_f32_16x16x128_f8f6f4(
              av[mi], bv, acc[mi][ni], 0, 0, 0, 127, 0, 127);
      }
      __syncthreads();          // all waves done reading this k-block
      if (it < 3) {
        ISSUE_DMA(i0, j0, (it + 1) * 128)
        __syncthreads();        // drain
      }
    }

    // save tile params for epilogue, advance to next tile, prefetch its iter0
    const int e_i0 = i0, e_j0 = j0, e_gidx = gidx;
    const bool e_diag = diagblk, e_valid = valid;
    gidx++;
    if (tt == 0) {
      if (++bj >= nb) { bi++; bj = bi; }       // next tile in triangle order
      i0 = bi * 128; j0 = bj * 128;
      if (gidx < total) ISSUE_DMA(i0, j0, 0)   // latency covered by epilogue
    }

    // ---- epilogue for the just-computed tile (stats in sf, not As/Bs) ----
    if (e_valid) {
      const int colbase = e_j0 + wcol * 64 + l15;
      int clab[4];
      #pragma unroll
      for (int ni = 0; ni < 4; ni++) clab[ni] = glab[colbase + ni * 16];

      float colE[4] = {0.f, 0.f, 0.f, 0.f};
      float colP[4] = {0.f, 0.f, 0.f, 0.f};

      #pragma unroll
      for (int mi = 0; mi < 4; mi++) {
        const int lrw = wrow * 64 + mi * 16 + quad * 4;
        #pragma unroll
        for (int r = 0; r < 4; r++) {
          const int row = e_i0 + lrw + r;
          const int rlab = glab[row];
          float Ssum = 0.f, Psum = 0.f;
          #pragma unroll
          for (int ni = 0; ni < 4; ni++) {
            const int col = colbase + ni * 16;
            const float val = acc[mi][ni][r];
            const float lg = fmaf(val, T1S, -TEMP_INV);  // (sim - 1)/T
            const bool diag = e_diag && (row == col);
            const float e = diag ? 0.f : __expf(lg);
            const float pm = (!diag && rlab == clab[ni]) ? lg : 0.f;
            Ssum += e; Psum += pm;
            colE[ni] += e; colP[ni] += pm;
          }
          #pragma unroll
          for (int off = 8; off; off >>= 1) {
            Ssum += __shfl_xor(Ssum, off, 64);
            Psum += __shfl_xor(Psum, off, 64);
          }
          if (l15 == 0) {
            sf[wcol * 128 + lrw + r]       = Ssum;
            sf[256 + wcol * 128 + lrw + r] = Psum;
          }
        }
      }
      if (!e_diag) {
        #pragma unroll
        for (int ni = 0; ni < 4; ni++) {
          float e = colE[ni];
          float p = colP[ni];
          e += __shfl_xor(e, 16, 64);
          e += __shfl_xor(e, 32, 64);
          p += __shfl_xor(p, 16, 64);
          p += __shfl_xor(p, 32, 64);
          const int lcol = wcol * 64 + ni * 16 + l15;
          if (quad == 0) {
            sf[512 + wrow * 128 + lcol] = e;
            sf[768 + wrow * 128 + lcol] = p;
          }
        }
      }
    }
    __syncthreads();   // stats visible; ALSO drains next tile's iter0 DMAs
    if (e_valid) {
      float* dst = part + (size_t)e_gidx * 512;
      if (t < 128) {
        dst[t]       = sf[t] + sf[128 + t];          // rowS
        dst[128 + t] = sf[256 + t] + sf[384 + t];    // rowP
      } else if (!e_diag) {
        const int u = t - 128;
        dst[256 + u] = sf[512 + u] + sf[640 + u];    // colS
        dst[384 + u] = sf[768 + u] + sf[896 + u];    // colP
      }
    }
    __syncthreads();   // sf reads done before next tile's epilogue overwrites
  }
}

// ---- gather partials (8-way sliced) + in-block histogram -> loss ----
__global__ __launch_bounds__(1024) void reduce_loss_k(const float* __restrict__ part,
                                                      const int* __restrict__ glab,
                                                      const int* __restrict__ labels,
                                                      const int* __restrict__ kptr,
                                                      float* __restrict__ gacc,
                                                      int* __restrict__ dcnt,
                                                      float* __restrict__ out, int N) {
  const int nb = N / 128;
  const int b = blockIdx.x;
  const int tt = threadIdx.x;
  const int t = tt & 127;
  const int sl = tt >> 7;
  const int k = *kptr;
  const int B = N / k;

  __shared__ int h[64];
  if (tt < 64) h[tt] = 0;
  __syncthreads();
  for (int g = tt; g < B; g += 1024) {
    int lb = labels[(size_t)g * k];
    if (lb >= 0 && lb < 64) atomicAdd(&h[lb], 1);
  }

  float S = 0.f, P = 0.f;
  const int base = b * nb - b * (b - 1) / 2;
  for (int bj = b + sl; bj < nb; bj += 8) {
    const float* p = part + (size_t)(base + bj - b) * 512;
    S += p[t];
    P += p[128 + t];
  }
  for (int bi = sl; bi < b; bi += 8) {
    const int idx = bi * nb - bi * (bi - 1) / 2 + (b - bi);
    const float* p = part + (size_t)idx * 512;
    S += p[256 + t];
    P += p[384 + t];
  }
  __shared__ float sS[8][128], sP[8][128];
  sS[sl][t] = S; sP[sl][t] = P;
  __syncthreads();
  float l = 0.f, v = 0.f;
  if (sl == 0) {
    S = 0.f; P = 0.f;
    #pragma unroll
    for (int s = 0; s < 8; s++) { S += sS[s][t]; P += sP[s][t]; }
    const int np = h[glab[b * 128 + t]] * k - 1;
    if (np > 0) {
      l = -(P - (float)np * logf(S + 1e-8f)) / (float)np;
      v = 1.f;
    }
  }
  #pragma unroll
  for (int off = 32; off; off >>= 1) {
    l += __shfl_xor(l, off, 64);
    v += __shfl_xor(v, off, 64);
  }
  __shared__ float sl16[16], sv16[16];
  if ((tt & 63) == 0) { sl16[tt >> 6] = l; sv16[tt >> 6] = v; }
  __syncthreads();
  if (tt == 0) {
    float L = 0.f, V = 0.f;
    #pragma unroll
    for (int i = 0; i < 16; i++) { L += sl16[i]; V += sv16[i]; }
    atomicAdd(&gacc[0], L);
    atomicAdd(&gacc[1], V);
    __threadfence();
    const int prev = atomicAdd(dcnt, 1);
    if (prev == (int)gridDim.x - 1) {
      const float Lf = atomicAdd(&gacc[0], 0.f);
      const float Vf = atomicAdd(&gacc[1], 0.f);
      out[0] = Lf / fmaxf(Vf, 1.f);
    }
  }
}

extern "C" void kernel_launch(void* const* d_in, const int* in_sizes, int n_in,
                              void* d_out, int out_size, void* d_ws, size_t ws_size,
                              hipStream_t stream) {
  const float* feat = (const float*)d_in[0];
  const int* labels = (const int*)d_in[1];
  const int* kptr   = (const int*)d_in[2];
  const int N = in_sizes[1];
  const int D = in_sizes[0] / N;  // 512

  const int nb = N / 128;
  const int total = nb * (nb + 1) / 2;
  const int npairs = (total + 1) / 2;

  char* ws = (char*)d_ws;
  uchar* fq = (uchar*)ws;
  size_t off = (size_t)N * D;
  float* part = (float*)(ws + off); off += (size_t)total * 512 * sizeof(float);
  int* glab   = (int*)(ws + off);   off += (size_t)N * sizeof(int);
  float* gacc = (float*)(ws + off); off += 2 * sizeof(float);
  int* dcnt   = (int*)(ws + off);   off += sizeof(int);

  norm_k<<<(N + 3) / 4, 256, 0, stream>>>(feat, fq, labels, kptr, glab,
                                          gacc, dcnt, N, D);
  gemm_k<<<npairs, 256, 0, stream>>>(fq, glab, part, N, D);
  reduce_loss_k<<<nb, 1024, 0, stream>>>(part, glab, labels, kptr, gacc, dcnt,
                                         (float*)d_out, N);
}

// Round 15
// 128.999 us; speedup vs baseline: 3.5698x; 3.5698x over previous
//
#include <hip/hip_runtime.h>
#include <hip/hip_bf16.h>

#define TEMP_INV 14.285714285714286f  // 1/0.07
#define FSCALE 16.0f                  // fp8 pre-scale per operand
#define T1S (TEMP_INV / 256.0f)       // acc = 256*sim -> (sim-1)/T = acc*T1S - TEMP_INV

typedef __attribute__((ext_vector_type(4))) float f32x4;
typedef __attribute__((ext_vector_type(4))) int i32x4;
typedef __attribute__((ext_vector_type(8))) int i32x8;

#define ASYNC_COPY16(gp, lp)                                                  \
  __builtin_amdgcn_global_load_lds(                                          \
      (__attribute__((address_space(1))) const void*)(gp),                    \
      (__attribute__((address_space(3))) void*)(lp), 16, 0, 0)

// ---- row L2-normalize -> fp8 e4m3 (x16) in QUAD-MAJOR layout ----
// Distributed glab fill (4 rows/block, 1 write/wave); block 0 only zeroes
// gacc/dcnt. No histogram here (reduce_loss recomputes it in parallel).
__global__ __launch_bounds__(256) void norm_k(const float* __restrict__ feat,
                                              uchar* __restrict__ fq,
                                              const int* __restrict__ labels,
                                              const int* __restrict__ kptr,
                                              int* __restrict__ glab,
                                              float* __restrict__ gacc,
                                              int* __restrict__ dcnt,
                                              int N, int D) {
  const int row = (blockIdx.x * 256 + threadIdx.x) >> 6;
  const int lane = threadIdx.x & 63;
  if (row < N) {
    const float4* fr = (const float4*)(feat + (size_t)row * D);
    float4 v0 = fr[lane * 2];
    float4 v1 = fr[lane * 2 + 1];
    float ss = v0.x * v0.x + v0.y * v0.y + v0.z * v0.z + v0.w * v0.w +
               v1.x * v1.x + v1.y * v1.y + v1.z * v1.z + v1.w * v1.w;
    #pragma unroll
    for (int off = 32; off; off >>= 1) ss += __shfl_xor(ss, off, 64);
    const float inv = FSCALE / fmaxf(sqrtf(ss), 1e-12f);
    int w0 = 0, w1 = 0;
    w0 = __builtin_amdgcn_cvt_pk_fp8_f32(v0.x * inv, v0.y * inv, w0, false);
    w0 = __builtin_amdgcn_cvt_pk_fp8_f32(v0.z * inv, v0.w * inv, w0, true);
    w1 = __builtin_amdgcn_cvt_pk_fp8_f32(v1.x * inv, v1.y * inv, w1, false);
    w1 = __builtin_amdgcn_cvt_pk_fp8_f32(v1.z * inv, v1.w * inv, w1, true);
    uint2 o; o.x = (uint)w0; o.y = (uint)w1;
    const int pofs = (lane >> 4) * 128 + (lane & 3) * 32 + ((lane >> 2) & 3) * 8;
    *(uint2*)(fq + (size_t)row * D + pofs) = o;
    if (lane == 0) {
      const int k = *kptr;
      glab[row] = labels[(size_t)(row / k) * k];
    }
  }
  if (blockIdx.x == 0 && threadIdx.x < 3) {
    if (threadIdx.x < 2) gacc[threadIdx.x] = 0.f;
    else *dcnt = 0;
  }
}

// ---- fused MX-fp8 GEMM + masked-softmax-stats, upper-triangle blocks ----
// (r13's proven kernel: 128x128 tile, BK=128 fp8 bytes, 4 waves, 4x4 frags,
// ONE mfma_scale_f32_16x16x128_f8f6f4 (scales=1.0) per frag per k-block.)
__global__ __launch_bounds__(256, 4) void gemm_k(const uchar* __restrict__ fq,
                                                 const int* __restrict__ glab,
                                                 float* __restrict__ part,
                                                 int N, int D) {
  __shared__ uchar As[128 * 128];
  __shared__ uchar Bs[128 * 128];
  const int t = threadIdx.x;
  const int lane = t & 63;
  const int wid = t >> 6;
  const int wrow = wid >> 1, wcol = wid & 1;
  const int quad = lane >> 4, l15 = lane & 15;

  const int nb = N / 128;
  const int total = nb * (nb + 1) / 2;
  int gidx = blockIdx.x;
  if ((total & 7) == 0) {
    const int per = total >> 3;
    gidx = (blockIdx.x & 7) * per + (blockIdx.x >> 3);
  }
  int idx = gidx, bi = 0;
  while (idx >= nb - bi) { idx -= nb - bi; bi++; }
  const int bj = bi + idx;
  const int i0 = bi * 128, j0 = bj * 128;
  const bool diagblk = (bi == bj);

  f32x4 acc[4][4];
  #pragma unroll
  for (int mi = 0; mi < 4; mi++)
    #pragma unroll
    for (int ni = 0; ni < 4; ni++) {
      f32x4 z = {0.f, 0.f, 0.f, 0.f};
      acc[mi][ni] = z;
    }

  uchar* sb = (wid < 2) ? As : Bs;
  const int rbase = (wid & 1) * 64;
  const int rowstart = ((wid < 2) ? i0 : j0) + rbase;
  const int lrow = lane >> 3;
  const int lch = lane & 7;

  for (int kb = 0; kb < D; kb += 128) {
    __syncthreads();
    #pragma unroll
    for (int i = 0; i < 8; i++) {
      const int rl = 8 * i + lrow;
      const int cg = lch ^ (rl & 7);
      ASYNC_COPY16(fq + (size_t)(rowstart + rl) * D + kb + cg * 16,
                   sb + (rbase + 8 * i) * 128);
    }
    __syncthreads();
    i32x8 av[4];
    #pragma unroll
    for (int mi = 0; mi < 4; mi++) {
      const int r = wrow * 64 + mi * 16 + l15;
      i32x4 lo = *(const i32x4*)&As[r * 128 + (((2 * quad) ^ (r & 7)) << 4)];
      i32x4 hi = *(const i32x4*)&As[r * 128 + (((2 * quad + 1) ^ (r & 7)) << 4)];
      av[mi] = (i32x8){lo.x, lo.y, lo.z, lo.w, hi.x, hi.y, hi.z, hi.w};
    }
    #pragma unroll
    for (int ni = 0; ni < 4; ni++) {
      const int r = wcol * 64 + ni * 16 + l15;
      i32x4 lo = *(const i32x4*)&Bs[r * 128 + (((2 * quad) ^ (r & 7)) << 4)];
      i32x4 hi = *(const i32x4*)&Bs[r * 128 + (((2 * quad + 1) ^ (r & 7)) << 4)];
      i32x8 bv = (i32x8){lo.x, lo.y, lo.z, lo.w, hi.x, hi.y, hi.z, hi.w};
      #pragma unroll
      for (int mi = 0; mi < 4; mi++)
        acc[mi][ni] = __builtin_amdgcn_mfma_scale_f32_16x16x128_f8f6f4(
            av[mi], bv, acc[mi][ni], 0, 0, 0, 127, 0, 127);
    }
  }

  __syncthreads();
  float* sf = (float*)As;
  const int colbase = j0 + wcol * 64 + l15;
  int clab[4];
  #pragma unroll
  for (int ni = 0; ni < 4; ni++) clab[ni] = glab[colbase + ni * 16];

  float colE[4] = {0.f, 0.f, 0.f, 0.f};
  float colP[4] = {0.f, 0.f, 0.f, 0.f};

  #pragma unroll
  for (int mi = 0; mi < 4; mi++) {
    const int lrw = wrow * 64 + mi * 16 + quad * 4;
    #pragma unroll
    for (int r = 0; r < 4; r++) {
      const int row = i0 + lrw + r;
      const int rlab = glab[row];
      float Ssum = 0.f, Psum = 0.f;
      #pragma unroll
      for (int ni = 0; ni < 4; ni++) {
        const int col = colbase + ni * 16;
        const float val = acc[mi][ni][r];
        const float lg = fmaf(val, T1S, -TEMP_INV);
        const bool diag = diagblk && (row == col);
        const float e = diag ? 0.f : __expf(lg);
        const float pm = (!diag && rlab == clab[ni]) ? lg : 0.f;
        Ssum += e; Psum += pm;
        colE[ni] += e; colP[ni] += pm;
      }
      #pragma unroll
      for (int off = 8; off; off >>= 1) {
        Ssum += __shfl_xor(Ssum, off, 64);
        Psum += __shfl_xor(Psum, off, 64);
      }
      if (l15 == 0) {
        sf[wcol * 128 + lrw + r]       = Ssum;
        sf[256 + wcol * 128 + lrw + r] = Psum;
      }
    }
  }
  if (!diagblk) {
    #pragma unroll
    for (int ni = 0; ni < 4; ni++) {
      float e = colE[ni];
      float p = colP[ni];
      e += __shfl_xor(e, 16, 64);
      e += __shfl_xor(e, 32, 64);
      p += __shfl_xor(p, 16, 64);
      p += __shfl_xor(p, 32, 64);
      const int lcol = wcol * 64 + ni * 16 + l15;
      if (quad == 0) {
        sf[512 + wrow * 128 + lcol] = e;
        sf[768 + wrow * 128 + lcol] = p;
      }
    }
  }
  __syncthreads();
  float* dst = part + (size_t)gidx * 512;
  if (t < 128) {
    dst[t]       = sf[t] + sf[128 + t];
    dst[128 + t] = sf[256 + t] + sf[384 + t];
  } else if (!diagblk) {
    const int u = t - 128;
    dst[256 + u] = sf[512 + u] + sf[640 + u];
    dst[384 + u] = sf[768 + u] + sf[896 + u];
  }
}

// ---- gather partials (8-way sliced) + in-block histogram -> loss ----
__global__ __launch_bounds__(1024) void reduce_loss_k(const float* __restrict__ part,
                                                      const int* __restrict__ glab,
                                                      const int* __restrict__ labels,
                                                      const int* __restrict__ kptr,
                                                      float* __restrict__ gacc,
                                                      int* __restrict__ dcnt,
                                                      float* __restrict__ out, int N) {
  const int nb = N / 128;
  const int b = blockIdx.x;
  const int tt = threadIdx.x;
  const int t = tt & 127;    // row within strip
  const int sl = tt >> 7;    // slice 0..7
  const int k = *kptr;
  const int B = N / k;

  __shared__ int h[64];
  if (tt < 64) h[tt] = 0;
  __syncthreads();
  for (int g = tt; g < B; g += 1024) {
    int lb = labels[(size_t)g * k];
    if (lb >= 0 && lb < 64) atomicAdd(&h[lb], 1);
  }

  float S = 0.f, P = 0.f;
  const int base = b * nb - b * (b - 1) / 2;
  for (int bj = b + sl; bj < nb; bj += 8) {   // row-side partials
    const float* p = part + (size_t)(base + bj - b) * 512;
    S += p[t];
    P += p[128 + t];
  }
  for (int bi = sl; bi < b; bi += 8) {        // col-side partials (symmetry)
    const int idx = bi * nb - bi * (bi - 1) / 2 + (b - bi);
    const float* p = part + (size_t)idx * 512;
    S += p[256 + t];
    P += p[384 + t];
  }
  __shared__ float sS[8][128], sP[8][128];
  sS[sl][t] = S; sP[sl][t] = P;
  __syncthreads();
  float l = 0.f, v = 0.f;
  if (sl == 0) {
    S = 0.f; P = 0.f;
    #pragma unroll
    for (int s = 0; s < 8; s++) { S += sS[s][t]; P += sP[s][t]; }
    const int np = h[glab[b * 128 + t]] * k - 1;
    if (np > 0) {
      l = -(P - (float)np * logf(S + 1e-8f)) / (float)np;
      v = 1.f;
    }
  }
  #pragma unroll
  for (int off = 32; off; off >>= 1) {
    l += __shfl_xor(l, off, 64);
    v += __shfl_xor(v, off, 64);
  }
  __shared__ float sl16[16], sv16[16];
  if ((tt & 63) == 0) { sl16[tt >> 6] = l; sv16[tt >> 6] = v; }
  __syncthreads();
  if (tt == 0) {
    float L = 0.f, V = 0.f;
    #pragma unroll
    for (int i = 0; i < 16; i++) { L += sl16[i]; V += sv16[i]; }
    atomicAdd(&gacc[0], L);
    atomicAdd(&gacc[1], V);
    __threadfence();
    const int prev = atomicAdd(dcnt, 1);
    if (prev == (int)gridDim.x - 1) {
      const float Lf = atomicAdd(&gacc[0], 0.f);
      const float Vf = atomicAdd(&gacc[1], 0.f);
      out[0] = Lf / fmaxf(Vf, 1.f);
    }
  }
}

extern "C" void kernel_launch(void* const* d_in, const int* in_sizes, int n_in,
                              void* d_out, int out_size, void* d_ws, size_t ws_size,
                              hipStream_t stream) {
  const float* feat = (const float*)d_in[0];
  const int* labels = (const int*)d_in[1];
  const int* kptr   = (const int*)d_in[2];
  const int N = in_sizes[1];
  const int D = in_sizes[0] / N;  // 512

  const int nb = N / 128;
  const int total = nb * (nb + 1) / 2;

  char* ws = (char*)d_ws;
  uchar* fq = (uchar*)ws;
  size_t off = (size_t)N * D;  // fp8: 1 byte/elem
  float* part = (float*)(ws + off); off += (size_t)total * 512 * sizeof(float);
  int* glab   = (int*)(ws + off);   off += (size_t)N * sizeof(int);
  float* gacc = (float*)(ws + off); off += 2 * sizeof(float);
  int* dcnt   = (int*)(ws + off);   off += sizeof(int);

  norm_k<<<(N + 3) / 4, 256, 0, stream>>>(feat, fq, labels, kptr, glab,
                                          gacc, dcnt, N, D);
  gemm_k<<<total, 256, 0, stream>>>(fq, glab, part, N, D);
  reduce_loss_k<<<nb, 1024, 0, stream>>>(part, glab, labels, kptr, gacc, dcnt,
                                         (float*)d_out, N);
}